// Round 3
// baseline (831.100 us; speedup 1.0000x reference)
//
#include <hip/hip_runtime.h>
#include <hip/hip_bf16.h>

// ---------------------------------------------------------------------------
// BYOGPT forward: embed+PE -> 4x[QKV proj, flash-attn, LN, lin, LN] -> unembed
// B=2 S=1024 D=768 H=12 Dh=64 V=50257. bf16 MFMA GEMMs, fp32 residual/LN.
// R3: unembed moves to 256x256-tile 8-wave dbuf GEMM with counted vmcnt
//     (raw s_barrier + inline-asm waitcnt, 2-tile-ahead staging, T2+T4+T5+T1).
// ---------------------------------------------------------------------------

#define VOCAB 50257
#define DM 768
#define NL 4
#define NH 12
#define DH 64
#define SEQ 1024
#define BATCH 2
#define ROWS (BATCH * SEQ)   // 2048
#define QKVN (3 * DM)        // 2304

typedef __attribute__((ext_vector_type(8))) short short8;
typedef __attribute__((ext_vector_type(4))) float f32x4;

__device__ __forceinline__ unsigned short f2bf(float f) {
    union { float f; unsigned u; } v; v.f = f;
    unsigned r = v.u + 0x7FFFu + ((v.u >> 16) & 1u);   // RNE
    return (unsigned short)(r >> 16);
}

#define GLOAD16(gp, lp)                                                        \
    __builtin_amdgcn_global_load_lds(                                          \
        (const __attribute__((address_space(1))) unsigned int*)(gp),           \
        (__attribute__((address_space(3))) unsigned int*)(lp), 16, 0, 0)

// ---------------- fp32 -> bf16 bulk convert ---------------------------------
__global__ __launch_bounds__(256) void cvt_kernel(const float* __restrict__ in,
                                                  unsigned short* __restrict__ out,
                                                  int n4) {
    int i = blockIdx.x * 256 + threadIdx.x;
    if (i < n4) {
        float4 v = ((const float4*)in)[i];
        ushort4 o;
        o.x = f2bf(v.x); o.y = f2bf(v.y); o.z = f2bf(v.z); o.w = f2bf(v.w);
        ((ushort4*)out)[i] = o;
    }
}

// pack wq/wk/wv (fp32) -> per-layer [2304][768] bf16
__global__ __launch_bounds__(256) void cvt_qkv_kernel(const float* __restrict__ wq,
                                                      const float* __restrict__ wk,
                                                      const float* __restrict__ wv,
                                                      unsigned short* __restrict__ dst,
                                                      int n4) {
    int i = blockIdx.x * 256 + threadIdx.x;
    if (i >= n4) return;
    const int PER_L = 3 * DM * DM / 4, PER_W = DM * DM / 4;
    int l = i / PER_L;
    int rem = i - l * PER_L;
    int w = rem / PER_W;
    int r2 = rem - w * PER_W;
    const float* src = (w == 0) ? wq : (w == 1) ? wk : wv;
    float4 v = ((const float4*)src)[(size_t)l * PER_W + r2];
    ushort4 o;
    o.x = f2bf(v.x); o.y = f2bf(v.y); o.z = f2bf(v.z); o.w = f2bf(v.w);
    ((ushort4*)dst)[i] = o;
}

__global__ __launch_bounds__(256) void pack_qkv_bias(const float* __restrict__ bq,
                                                     const float* __restrict__ bk,
                                                     const float* __restrict__ bv,
                                                     float* __restrict__ dst) {
    int i = blockIdx.x * 256 + threadIdx.x;   // NL*2304
    if (i >= NL * QKVN) return;
    int l = i / QKVN, c = i - l * QKVN;
    int w = c / DM, cc = c - w * DM;
    const float* src = (w == 0) ? bq : (w == 1) ? bk : bv;
    dst[i] = src[l * DM + cc];
}

// ---------------- embedding + positional encoding --------------------------
__global__ __launch_bounds__(256) void embed_kernel(const int* __restrict__ tok,
                                                    const float* __restrict__ emb,
                                                    const float* __restrict__ pe,
                                                    float* __restrict__ xf,
                                                    unsigned short* __restrict__ xb) {
    int row = blockIdx.x;                 // 0..2047
    int t = tok[row];
    int s = row & (SEQ - 1);
    #pragma unroll
    for (int j = 0; j < 3; ++j) {
        int c = threadIdx.x + j * 256;
        float v = emb[(size_t)t * DM + c] + pe[(size_t)s * DM + c];
        xf[(size_t)row * DM + c] = v;
        xb[(size_t)row * DM + c] = f2bf(v);
    }
}

// ---------------- residual + LayerNorm (writes fp32 + bf16) ----------------
__device__ __forceinline__ float block_sum(float x, float* red) {
    #pragma unroll
    for (int off = 32; off > 0; off >>= 1) x += __shfl_down(x, off);
    int w = threadIdx.x >> 6;
    if ((threadIdx.x & 63) == 0) red[w] = x;
    __syncthreads();
    float t = (red[0] + red[1]) + (red[2] + red[3]);
    __syncthreads();
    return t;
}

__global__ __launch_bounds__(256) void ln_kernel(const float* __restrict__ A,
                                                 const float* __restrict__ Bi,
                                                 const float* __restrict__ sc,
                                                 const float* __restrict__ bi,
                                                 float* __restrict__ xf,
                                                 unsigned short* __restrict__ xb) {
    __shared__ float red[4];
    int row = blockIdx.x, tid = threadIdx.x;
    const float* ap = A + (size_t)row * DM;
    const float* bp = Bi + (size_t)row * DM;
    float v[3], sum = 0.f;
    #pragma unroll
    for (int j = 0; j < 3; ++j) { v[j] = ap[tid + j * 256] + bp[tid + j * 256]; sum += v[j]; }
    sum = block_sum(sum, red);
    float mean = sum * (1.f / DM);
    float vs = 0.f;
    #pragma unroll
    for (int j = 0; j < 3; ++j) { float d = v[j] - mean; vs += d * d; }
    vs = block_sum(vs, red);
    float rstd = rsqrtf(vs * (1.f / DM) + 1e-5f);
    #pragma unroll
    for (int j = 0; j < 3; ++j) {
        int c = tid + j * 256;
        float o = (v[j] - mean) * rstd * sc[c] + bi[c];
        xf[(size_t)row * DM + c] = o;
        xb[(size_t)row * DM + c] = f2bf(o);
    }
}

// ---------------- 128x128-tile bf16 GEMM (layer GEMMs) ---------------------
template <int OUT_BF16>
__global__ __launch_bounds__(256) void gemm128(const unsigned short* __restrict__ A,
                                               const unsigned short* __restrict__ B,
                                               const float* __restrict__ bias,
                                               void* __restrict__ C,
                                               int M, int N, int K, int gx) {
    __shared__ __align__(16) unsigned short As[128 * 64];
    __shared__ __align__(16) unsigned short Bs[128 * 64];
    int bid = blockIdx.x;
    const int nwg = gridDim.x;
    if ((nwg & 7) == 0) {                       // chunked XCD swizzle
        int q = nwg >> 3;
        bid = (bid & 7) * q + (bid >> 3);
    }
    const int bx = bid % gx, by = bid / gx;
    const int m0 = bx * 128, n0 = by * 128;
    const int tid = threadIdx.x, lane = tid & 63, wid = tid >> 6;
    const int wm = wid >> 1, wn = wid & 1;      // wave -> 64x64 quadrant
    const int lr = lane & 15, lq = lane >> 4;

    const int sr = wid * 32 + (lane >> 3);
    const int sch = lane & 7;
    const int scs = sch ^ (sr & 7);
    const unsigned short* aP[4];
    const unsigned short* bP[4];
    unsigned short* aL[4];
    unsigned short* bL[4];
    #pragma unroll
    for (int i = 0; i < 4; ++i) {
        int r = sr + i * 8;
        aP[i] = A + (size_t)(m0 + r) * K + scs * 8;
        int br = n0 + r; if (br >= N) br = N - 1;
        bP[i] = B + (size_t)br * K + scs * 8;
        aL[i] = &As[r * 64 + sch * 8];
        bL[i] = &Bs[r * 64 + sch * 8];
    }

    f32x4 acc[4][4] = {};

    for (int k0 = 0; k0 < K; k0 += 64) {
        #pragma unroll
        for (int i = 0; i < 4; ++i) GLOAD16(aP[i] + k0, aL[i]);
        #pragma unroll
        for (int i = 0; i < 4; ++i) GLOAD16(bP[i] + k0, bL[i]);
        __syncthreads();
        #pragma unroll
        for (int kk = 0; kk < 2; ++kk) {
            short8 a[4], b[4];
            #pragma unroll
            for (int i = 0; i < 4; ++i) {
                int ar = wm * 64 + i * 16 + lr;
                a[i] = *reinterpret_cast<const short8*>(
                    &As[ar * 64 + (((kk * 4 + lq) ^ (ar & 7)) * 8)]);
                int br = wn * 64 + i * 16 + lr;
                b[i] = *reinterpret_cast<const short8*>(
                    &Bs[br * 64 + (((kk * 4 + lq) ^ (br & 7)) * 8)]);
            }
            #pragma unroll
            for (int i = 0; i < 4; ++i)
                #pragma unroll
                for (int j = 0; j < 4; ++j)
                    acc[i][j] = __builtin_amdgcn_mfma_f32_16x16x32_bf16(a[i], b[j], acc[i][j], 0, 0, 0);
        }
        __syncthreads();
    }
    #pragma unroll
    for (int i = 0; i < 4; ++i) {
        int row = m0 + wm * 64 + i * 16 + lq * 4;
        #pragma unroll
        for (int j = 0; j < 4; ++j) {
            int col = n0 + wn * 64 + j * 16 + lr;
            if (col < N) {
                float bv = bias[col];
                #pragma unroll
                for (int r = 0; r < 4; ++r) {
                    float v = acc[i][j][r] + bv;
                    if (OUT_BF16) ((unsigned short*)C)[(size_t)(row + r) * N + col] = f2bf(v);
                    else          ((float*)C)[(size_t)(row + r) * N + col] = v;
                }
            }
        }
    }
}

// ---------------- 256x256-tile 8-wave dbuf GEMM (unembed) ------------------
// Counted-vmcnt schedule: raw s_barrier + inline-asm waitcnt; stage kt+2 into
// the buffer just freed by this iteration's reads; vmcnt(8) keeps the newest
// 8 global_load_lds in flight across both barriers (T4). T2 swizzle, T5
// setprio, T1 chunked XCD swizzle. 512 threads, waves 2(M)x4(N), 128x64/wave.
template <int OUT_BF16>
__global__ __launch_bounds__(512, 2) void gemm256(const unsigned short* __restrict__ A,
                                                  const unsigned short* __restrict__ B,
                                                  const float* __restrict__ bias,
                                                  void* __restrict__ C,
                                                  int M, int N, int K, int gx) {
    __shared__ __align__(16) unsigned short As[2][256 * 64];
    __shared__ __align__(16) unsigned short Bs[2][256 * 64];
    int bid = blockIdx.x;
    const int nwg = gridDim.x;
    if ((nwg & 7) == 0) { int q = nwg >> 3; bid = (bid & 7) * q + (bid >> 3); }
    const int bx = bid % gx, by = bid / gx;
    const int m0 = bx * 256, n0 = by * 256;
    const int tid = threadIdx.x, lane = tid & 63, wid = tid >> 6;
    const int wm = wid >> 2, wn = wid & 3;      // 2x4 wave grid
    const int lr = lane & 15, lq = lane >> 4;

    // staging: thread tid covers LDS byte offset tid*16 (+ issue*64 rows)
    const int sr = tid >> 3;                    // 0..63
    const int sch = tid & 7;
    const int scs = sch ^ (sr & 7);             // inverse-swizzled source chunk
    const unsigned short* aP[4];
    const unsigned short* bP[4];
    #pragma unroll
    for (int i = 0; i < 4; ++i) {
        int r = sr + i * 64;                    // (r&7)==(sr&7)
        aP[i] = A + (size_t)(m0 + r) * K + scs * 8;
        int br = n0 + r; if (br >= N) br = N - 1;
        bP[i] = B + (size_t)br * K + scs * 8;
    }

    #define STAGE256(kt, c)                                                    \
        do {                                                                   \
            const int _ko = (kt) * 64;                                         \
            _Pragma("unroll")                                                  \
            for (int _i = 0; _i < 4; ++_i)                                     \
                GLOAD16(aP[_i] + _ko, &As[c][(sr + _i * 64) * 64 + sch * 8]);  \
            _Pragma("unroll")                                                  \
            for (int _i = 0; _i < 4; ++_i)                                     \
                GLOAD16(bP[_i] + _ko, &Bs[c][(sr + _i * 64) * 64 + sch * 8]);  \
        } while (0)

    f32x4 acc[8][4] = {};
    const int NT = K >> 6;                      // 12 for K=768

    STAGE256(0, 0);
    STAGE256(1, 1);
    asm volatile("s_waitcnt vmcnt(8)" ::: "memory");   // buf0's 8 done
    __builtin_amdgcn_s_barrier();

    for (int kt = 0; kt < NT; ++kt) {
        const int c = kt & 1;
        #pragma unroll
        for (int kk = 0; kk < 2; ++kk) {
            short8 af[8], bf[4];
            #pragma unroll
            for (int i = 0; i < 8; ++i) {
                int ar = wm * 128 + i * 16 + lr;
                af[i] = *reinterpret_cast<const short8*>(
                    &As[c][ar * 64 + (((kk * 4 + lq) ^ (ar & 7)) * 8)]);
            }
            #pragma unroll
            for (int j = 0; j < 4; ++j) {
                int br = wn * 64 + j * 16 + lr;
                bf[j] = *reinterpret_cast<const short8*>(
                    &Bs[c][br * 64 + (((kk * 4 + lq) ^ (br & 7)) * 8)]);
            }
            __builtin_amdgcn_s_setprio(1);
            #pragma unroll
            for (int i = 0; i < 8; ++i)
                #pragma unroll
                for (int j = 0; j < 4; ++j)
                    acc[i][j] = __builtin_amdgcn_mfma_f32_16x16x32_bf16(af[i], bf[j], acc[i][j], 0, 0, 0);
            __builtin_amdgcn_s_setprio(0);
        }
        // all my reads of buf c have completed (MFMA consumed them); fence + barrier
        asm volatile("s_waitcnt lgkmcnt(0)" ::: "memory");
        __builtin_amdgcn_s_barrier();           // all waves done reading buf c
        if (kt + 2 < NT) {
            STAGE256(kt + 2, c);                // refill freed buffer
            asm volatile("s_waitcnt vmcnt(8)" ::: "memory");   // kt+1's 8 done
        } else if (kt + 2 == NT) {
            asm volatile("s_waitcnt vmcnt(0)" ::: "memory");   // last tile ready
        }
        __builtin_amdgcn_s_barrier();           // buf 1-c ready for all waves
    }

    #pragma unroll
    for (int i = 0; i < 8; ++i) {
        int row = m0 + wm * 128 + i * 16 + lq * 4;
        #pragma unroll
        for (int j = 0; j < 4; ++j) {
            int col = n0 + wn * 64 + j * 16 + lr;
            if (col < N) {
                float bv = bias[col];
                #pragma unroll
                for (int r = 0; r < 4; ++r) {
                    float v = acc[i][j][r] + bv;
                    if (OUT_BF16) ((unsigned short*)C)[(size_t)(row + r) * N + col] = f2bf(v);
                    else          ((float*)C)[(size_t)(row + r) * N + col] = v;
                }
            }
        }
    }
    #undef STAGE256
}

// ---------------- flash attention (causal), bf16 MFMA ----------------------
__global__ __launch_bounds__(256) void attn_kernel(const unsigned short* __restrict__ Q,
                                                   const unsigned short* __restrict__ K,
                                                   const unsigned short* __restrict__ V,
                                                   int ld,
                                                   float* __restrict__ O) {
    __shared__ __align__(16) unsigned short Ks[64 * 64];
    __shared__ __align__(16) unsigned short Vs[64 * 64];     // transposed [d][kv]
    __shared__ __align__(16) unsigned short Ps[4][16 * 64];  // per-wave P tile
    const int qb = blockIdx.x;
    const int bh = blockIdx.y;
    const int b = bh / NH, h = bh % NH;
    const int tid = threadIdx.x, lane = tid & 63, w = tid >> 6;
    const int lr = lane & 15, lq = lane >> 4;
    const int wq0 = qb * 64 + w * 16;
    const size_t base = (size_t)b * SEQ * ld + h * DH;
    const size_t obase = (size_t)b * SEQ * DM + h * DH;

    short8 qf[2];
    {
        const unsigned short* qp = Q + base + (size_t)(wq0 + lr) * ld + lq * 8;
        qf[0] = *reinterpret_cast<const short8*>(qp);
        qf[1] = *reinterpret_cast<const short8*>(qp + 32);
    }
    f32x4 o_acc[4] = {};
    float mrow[4], lrow[4];
    #pragma unroll
    for (int r = 0; r < 4; ++r) { mrow[r] = -1e30f; lrow[r] = 0.f; }

    const int srow = tid >> 3, scol = (tid & 7) * 8;
    for (int t = 0; t <= qb; ++t) {
        const int kv0 = t * 64;
        #pragma unroll
        for (int rr = 0; rr < 2; ++rr) {
            int row = rr * 32 + srow;
            {
                const unsigned short* kp = K + base + (size_t)(kv0 + row) * ld + scol;
                short8 v = *reinterpret_cast<const short8*>(kp);
                *reinterpret_cast<short8*>(&Ks[(row * 64 + scol) ^ ((row & 7) << 3)]) = v;
            }
            {
                const unsigned short* vp = V + base + (size_t)(kv0 + row) * ld + scol;
                short8 v = *reinterpret_cast<const short8*>(vp);
                #pragma unroll
                for (int j = 0; j < 8; ++j) {
                    int d = scol + j;
                    Vs[(d * 64 + row) ^ ((d & 7) << 3)] = (unsigned short)v[j];
                }
            }
        }
        __syncthreads();
        if (kv0 <= wq0 + 15) {
            f32x4 s[4];
            #pragma unroll
            for (int n = 0; n < 4; ++n) {
                int br = n * 16 + lr;
                short8 b0 = *reinterpret_cast<const short8*>(&Ks[(br * 64 + lq * 8) ^ ((br & 7) << 3)]);
                short8 b1 = *reinterpret_cast<const short8*>(&Ks[(br * 64 + 32 + lq * 8) ^ ((br & 7) << 3)]);
                f32x4 z = {};
                z = __builtin_amdgcn_mfma_f32_16x16x32_bf16(qf[0], b0, z, 0, 0, 0);
                z = __builtin_amdgcn_mfma_f32_16x16x32_bf16(qf[1], b1, z, 0, 0, 0);
                s[n] = z;
            }
            const bool diag = (t == qb);
            #pragma unroll
            for (int n = 0; n < 4; ++n)
                #pragma unroll
                for (int r = 0; r < 4; ++r) {
                    float v = s[n][r] * 0.125f;
                    if (diag) {
                        int rg = wq0 + lq * 4 + r;
                        int cg = kv0 + n * 16 + lr;
                        if (cg > rg) v = -1e30f;
                    }
                    s[n][r] = v;
                }
            float f[4];
            #pragma unroll
            for (int r = 0; r < 4; ++r) {
                float mx = fmaxf(fmaxf(s[0][r], s[1][r]), fmaxf(s[2][r], s[3][r]));
                #pragma unroll
                for (int off = 1; off < 16; off <<= 1) mx = fmaxf(mx, __shfl_xor(mx, off));
                float mn = fmaxf(mrow[r], mx);
                f[r] = exp2f((mrow[r] - mn) * 1.44269504f);
                mrow[r] = mn;
            }
            #pragma unroll
            for (int n = 0; n < 4; ++n)
                #pragma unroll
                for (int r = 0; r < 4; ++r)
                    s[n][r] = exp2f((s[n][r] - mrow[r]) * 1.44269504f);
            #pragma unroll
            for (int r = 0; r < 4; ++r) {
                float ls = ((s[0][r] + s[1][r]) + (s[2][r] + s[3][r]));
                #pragma unroll
                for (int off = 1; off < 16; off <<= 1) ls += __shfl_xor(ls, off);
                lrow[r] = lrow[r] * f[r] + ls;
            }
            #pragma unroll
            for (int n = 0; n < 4; ++n)
                #pragma unroll
                for (int r = 0; r < 4; ++r) {
                    int pr = lq * 4 + r, pc = n * 16 + lr;
                    Ps[w][(pr * 64 + pc) ^ ((pr & 7) << 3)] = f2bf(s[n][r]);
                }
            #pragma unroll
            for (int n = 0; n < 4; ++n)
                #pragma unroll
                for (int r = 0; r < 4; ++r) o_acc[n][r] *= f[r];
            #pragma unroll
            for (int kk = 0; kk < 2; ++kk) {
                short8 pa = *reinterpret_cast<const short8*>(
                    &Ps[w][(lr * 64 + kk * 32 + lq * 8) ^ ((lr & 7) << 3)]);
                #pragma unroll
                for (int n = 0; n < 4; ++n) {
                    int vr = n * 16 + lr;
                    short8 bv = *reinterpret_cast<const short8*>(
                        &Vs[(vr * 64 + kk * 32 + lq * 8) ^ ((vr & 7) << 3)]);
                    o_acc[n] = __builtin_amdgcn_mfma_f32_16x16x32_bf16(pa, bv, o_acc[n], 0, 0, 0);
                }
            }
        }
        __syncthreads();
    }
    #pragma unroll
    for (int r = 0; r < 4; ++r) {
        float inv = 1.f / lrow[r];
        int row = wq0 + lq * 4 + r;
        #pragma unroll
        for (int n = 0; n < 4; ++n)
            O[obase + (size_t)row * DM + n * 16 + lr] = o_acc[n][r] * inv;
    }
}

// ---------------------------------------------------------------------------
extern "C" void kernel_launch(void* const* d_in, const int* in_sizes, int n_in,
                              void* d_out, int out_size, void* d_ws, size_t ws_size,
                              hipStream_t stream) {
    const int*   tokens   = (const int*)d_in[0];
    const float* embed    = (const float*)d_in[1];
    const float* pe       = (const float*)d_in[2];
    const float* wq_w     = (const float*)d_in[3];
    const float* wq_b     = (const float*)d_in[4];
    const float* wk_w     = (const float*)d_in[5];
    const float* wk_b     = (const float*)d_in[6];
    const float* wv_w     = (const float*)d_in[7];
    const float* wv_b     = (const float*)d_in[8];
    const float* lin_w    = (const float*)d_in[9];
    const float* lin_b    = (const float*)d_in[10];
    const float* n1_s     = (const float*)d_in[11];
    const float* n1_b     = (const float*)d_in[12];
    const float* n2_s     = (const float*)d_in[13];
    const float* n2_b     = (const float*)d_in[14];
    const float* unemb_w  = (const float*)d_in[15];
    const float* unemb_b  = (const float*)d_in[16];

    char* ws = (char*)d_ws;
    size_t off = 0;
    auto carve = [&](size_t bytes) { char* p = ws + off; off += (bytes + 255) & ~(size_t)255; return p; };
    float*          xf     = (float*)carve((size_t)ROWS * DM * 4);
    float*          yb     = (float*)carve((size_t)ROWS * DM * 4);
    unsigned short* xb     = (unsigned short*)carve((size_t)ROWS * DM * 2);
    unsigned short* qkv    = (unsigned short*)carve((size_t)ROWS * QKVN * 2);
    unsigned short* wqkv_h = (unsigned short*)carve((size_t)NL * QKVN * DM * 2);
    unsigned short* lin_h  = (unsigned short*)carve((size_t)NL * DM * DM * 2);
    unsigned short* ue_h   = (unsigned short*)carve((size_t)VOCAB * DM * 2);
    float*          qkvb   = (float*)carve((size_t)NL * QKVN * 4);

    {
        int nq4 = NL * QKVN * DM / 4;
        cvt_qkv_kernel<<<(nq4 + 255) / 256, 256, 0, stream>>>(wq_w, wk_w, wv_w, wqkv_h, nq4);
        int nl4 = NL * DM * DM / 4;
        cvt_kernel<<<(nl4 + 255) / 256, 256, 0, stream>>>(lin_w, lin_h, nl4);
        int nu4 = VOCAB * DM / 4;
        cvt_kernel<<<(nu4 + 255) / 256, 256, 0, stream>>>(unemb_w, ue_h, nu4);
        pack_qkv_bias<<<(NL * QKVN + 255) / 256, 256, 0, stream>>>(wq_b, wk_b, wv_b, qkvb);
    }
    embed_kernel<<<ROWS, 256, 0, stream>>>(tokens, embed, pe, xf, xb);

    const int gx = ROWS / 128;   // 16 M-blocks (128-tile)
    for (int l = 0; l < NL; ++l) {
        gemm128<1><<<gx * (QKVN / 128), 256, 0, stream>>>(
            xb, wqkv_h + (size_t)l * QKVN * DM, qkvb + l * QKVN, qkv,
            ROWS, QKVN, DM, gx);
        attn_kernel<<<dim3(SEQ / 64, BATCH * NH), 256, 0, stream>>>(
            qkv, qkv + DM, qkv + 2 * DM, QKVN, yb);
        ln_kernel<<<ROWS, 256, 0, stream>>>(xf, yb, n1_s + l * DM, n1_b + l * DM, xf, xb);
        gemm128<0><<<gx * (DM / 128), 256, 0, stream>>>(
            xb, lin_h + (size_t)l * DM * DM, lin_b + l * DM, yb,
            ROWS, DM, DM, gx);
        ln_kernel<<<ROWS, 256, 0, stream>>>(xf, yb, n2_s + l * DM, n2_b + l * DM, xf, xb);
    }
    // unembed: [2048,768] x [50257,768]^T -> d_out fp32, 256-tile dbuf GEMM
    const int gxu = ROWS / 256;                 // 8
    const int gyu = (VOCAB + 255) / 256;        // 197
    gemm256<0><<<gxu * gyu, 512, 0, stream>>>(
        xb, ue_h, unemb_b, (float*)d_out, ROWS, VOCAB, DM, gxu);
}